// Round 17
// baseline (26677.454 us; speedup 1.0000x reference)
//
#include <hip/hip_runtime.h>
#include <math.h>

#define Bb   256
#define Tt   512
#define INn  64
#define Hh   512
#define OUTn 96
#define NWG  256
#define TPB  512
#define SP   (Hh*Bb)   // one state plane in floats
#define HDR  12288     // ws header dwords: flags[2][4096] + rel @8192

struct Params {
  const float *Xt;          // [T][IN][B]
  float *H0, *H1;           // [2][H][B] each (ping-pong)
  unsigned int *flags;      // [2 groups][4096] padded arrival flags
  unsigned int *rel;        // rel[g*64] release words
  const float *Wih0,*Whh0,*bih0,*bhh0,*Wih1,*Whh1,*bih1,*bhh1;
  const float *dWih0,*dWhh0,*dbih0,*dbhh0,*dWih1,*dWhh1,*dbih1,*dbhh1;
  const float *projW,*projb;
  float *out;               // [B][OUT]
};

__device__ __forceinline__ float sigm(float x){ return 1.0f/(1.0f + expf(-x)); }

// Group-local barrier (proven R15): two independent 128-WG barriers.
template<int NR>
__device__ __forceinline__ void gridbar_g(unsigned int* flags, unsigned int* rel,
                                          unsigned int g, int bh, int rank) {
  __syncthreads();
  const int tid = threadIdx.x;
  unsigned int* gflags = flags + bh*4096;
  unsigned int* grel   = rel   + bh*64;
  if (rank == 0) {
    if (tid > 0 && tid < NR) {
      while (__hip_atomic_load(&gflags[tid*16], __ATOMIC_RELAXED, __HIP_MEMORY_SCOPE_AGENT) < g)
        __builtin_amdgcn_s_sleep(1);
    }
    __syncthreads();
    if (tid == 0) {
      __threadfence();
      __hip_atomic_store(grel, g, __ATOMIC_RELEASE, __HIP_MEMORY_SCOPE_AGENT);
    }
    __syncthreads();
  } else {
    if (tid == 0) {
      __threadfence();
      __hip_atomic_store(&gflags[rank*16], g, __ATOMIC_RELEASE, __HIP_MEMORY_SCOPE_AGENT);
      while (__hip_atomic_load(grel, __ATOMIC_RELAXED, __HIP_MEMORY_SCOPE_AGENT) < g)
        __builtin_amdgcn_s_sleep(1);
      __threadfence();
    }
    __syncthreads();
  }
}

// Transpose inputs [B][T][IN] -> Xt [T][IN][B]
__global__ void __launch_bounds__(256) xpose(const float* __restrict__ X, float* __restrict__ Xt) {
  __shared__ float tile[64][65];
  const int t = blockIdx.x;
  const int l = threadIdx.x & 63;
  const int r = threadIdx.x >> 6;   // 0..3
  for (int qd = 0; qd < 4; ++qd) {
    #pragma unroll
    for (int rep = 0; rep < 16; ++rep) {
      int bl = rep*4 + r;
      tile[bl][l] = X[(size_t)(qd*64 + bl)*(Tt*INn) + (size_t)t*INn + l];
    }
    __syncthreads();
    #pragma unroll
    for (int rep = 0; rep < 16; ++rep) {
      int i = rep*4 + r;
      Xt[(size_t)t*(INn*Bb) + (size_t)i*Bb + qd*64 + l] = tile[l][i];
    }
    __syncthreads();
  }
}

// in-wave reduction over kh (lane bits 3..5), 8-element arrays
#define BFLY8(a)                                                   \
  do { _Pragma("unroll")                                           \
    for (int m_ = 0; m_ < 8; ++m_) {                               \
      a[m_] += __shfl_xor(a[m_], 8, 64);                           \
      a[m_] += __shfl_xor(a[m_], 16, 64);                          \
      a[m_] += __shfl_xor(a[m_], 32, 64);                          \
    } } while (0)

#define LOAD8(dst, src)                                            \
  float dst[8];                                                    \
  { const float4 aA_ = *reinterpret_cast<const float4*>(src);      \
    const float4 aB_ = *reinterpret_cast<const float4*>((src)+4);  \
    dst[0]=aA_.x; dst[1]=aA_.y; dst[2]=aA_.z; dst[3]=aA_.w;        \
    dst[4]=aB_.x; dst[5]=aB_.y; dst[6]=aB_.z; dst[7]=aB_.w; }

// R17: 8 batches/thread halves LDS weight traffic (the measured co-limiter:
// 3.4MB/CU/phase @ ~85B/cyc = 16.7us > 10.7us VALU). kh (8-way) lives in lane
// bits 3..5; reduction = 3x shfl_xor (no LDS, no extra syncthreads).
// Weight rows padded (36/20 dwords) so the 8 kh-lanes' b128 reads hit
// disjoint bank quads (4*kh, 20*kh mod 32 all distinct).
// WG w: uw=w>>1 owns units 4uw..4uw+3; bh=w&1 owns batches 128bh..+127.
// Thread: bqlo=tid&7, kh=(tid>>3)&7, bqhi=(tid>>6)&1, h=tid>>7 (0..3);
//         bq=bqhi*8+bqlo (0..15), 8 batches each.
__global__ void __launch_bounds__(TPB, 2) lstm_main(Params P) {
  __shared__ float WA[512][36];  // [k][h*8 + (0..3: Wih1 ifgo | 4..7: Whh0)], pad 4
  __shared__ float WB[512][20];  // [k][h*4+g] Whh1 ; dec: dWhh0, pad 4
  __shared__ float WX[64][20];   // [k][h*4+g] Wih0, pad 4
  __shared__ float BS[32];       // combined biases
  __shared__ float PW[Hh];       // proj_W
  __shared__ float WXD[16];      // dec_Wih0 column
  __shared__ float PBs;          // proj_b

  const int tid  = threadIdx.x;
  const int w    = blockIdx.x;
  const int uw   = w >> 1;            // 0..127 -> units 4uw..4uw+3
  const int bh   = w & 1;             // batch half
  const int kh   = (tid >> 3) & 7;    // lane bits 3..5
  const int bq   = ((tid >> 6) & 1)*8 + (tid & 7);   // 0..15
  const int h    = tid >> 7;          // 0..3
  const int j    = 4*uw + h;
  const int h8   = h*8, h4 = h*4;
  const int boff = 128*bh + 8*bq;     // first owned batch (8 consecutive)
  unsigned int bgen = 1;

  // ---------------- encoder weight load ----------------
  for (int e = tid; e < 512*32; e += TPB) {
    int k = e >> 5, c = e & 31, hh = c >> 3, s = c & 7;
    int unit = 4*uw + hh;
    WA[k][c] = (s < 4) ? P.Wih1[(size_t)(s*Hh + unit)*Hh + k]
                       : P.Whh0[(size_t)((s-4)*Hh + unit)*Hh + k];
  }
  for (int e = tid; e < 512*16; e += TPB) {
    int k = e >> 4, c = e & 15, hh = c >> 2, g = c & 3;
    WB[k][c] = P.Whh1[(size_t)(g*Hh + 4*uw + hh)*Hh + k];
  }
  for (int e = tid; e < 64*16; e += TPB) {
    int k = e >> 4, c = e & 15, hh = c >> 2, g = c & 3;
    WX[k][c] = P.Wih0[(size_t)(g*Hh + 4*uw + hh)*INn + k];
  }
  if (tid < 32) {
    int c = tid, hh = c >> 3, s = c & 7;
    int unit = 4*uw + hh;
    BS[c] = (s < 4) ? (P.bih1[s*Hh+unit] + P.bhh1[s*Hh+unit])
                    : (P.bih0[(s-4)*Hh+unit] + P.bhh0[(s-4)*Hh+unit]);
  }
  __syncthreads();

  float c0[8] = {0,0,0,0,0,0,0,0}, c1[8] = {0,0,0,0,0,0,0,0};

  // ---------------- encoder phases ----------------
  for (int p = -1; p <= 511; ++p) {
    float z1i[8], z1f[8], z1g[8], z1o[8];
    float z0i[8], z0f[8], z0g[8], z0o[8];
    #pragma unroll
    for (int m = 0; m < 8; ++m) {
      z1i[m] = (kh==0) ? BS[h8+0] : 0.f; z1f[m] = (kh==0) ? BS[h8+1] : 0.f;
      z1g[m] = (kh==0) ? BS[h8+2] : 0.f; z1o[m] = (kh==0) ? BS[h8+3] : 0.f;
      z0i[m] = (kh==0) ? BS[h8+4] : 0.f; z0f[m] = (kh==0) ? BS[h8+5] : 0.f;
      z0g[m] = (kh==0) ? BS[h8+6] : 0.f; z0o[m] = (kh==0) ? BS[h8+7] : 0.f;
    }
    const float* __restrict__ h0in = P.H0 + (size_t)(p & 1)*SP + boff;      // h0(p)
    const float* __restrict__ h1in = P.H1 + (size_t)((p+1) & 1)*SP + boff;  // h1(p-1)
    #pragma unroll 2
    for (int kk = 0; kk < 64; ++kk) {
      const int k = kk*8 + kh;
      const float4 w1 = *reinterpret_cast<const float4*>(&WA[k][h8]);
      const float4 w0 = *reinterpret_cast<const float4*>(&WA[k][h8+4]);
      const float4 wb = *reinterpret_cast<const float4*>(&WB[k][h4]);
      LOAD8(hv, &h0in[k*Bb]);
      LOAD8(gv, &h1in[k*Bb]);
      #pragma unroll
      for (int m = 0; m < 8; ++m) {
        z1i[m]=fmaf(w1.x,hv[m],z1i[m]); z1f[m]=fmaf(w1.y,hv[m],z1f[m]);
        z1g[m]=fmaf(w1.z,hv[m],z1g[m]); z1o[m]=fmaf(w1.w,hv[m],z1o[m]);
        z0i[m]=fmaf(w0.x,hv[m],z0i[m]); z0f[m]=fmaf(w0.y,hv[m],z0f[m]);
        z0g[m]=fmaf(w0.z,hv[m],z0g[m]); z0o[m]=fmaf(w0.w,hv[m],z0o[m]);
        z1i[m]=fmaf(wb.x,gv[m],z1i[m]); z1f[m]=fmaf(wb.y,gv[m],z1f[m]);
        z1g[m]=fmaf(wb.z,gv[m],z1g[m]); z1o[m]=fmaf(wb.w,gv[m],z1o[m]);
      }
    }
    { // x-part: 8 K-rows per kh
      int tx = (p+1 < Tt) ? (p+1) : (Tt-1);
      const float* __restrict__ xin = P.Xt + (size_t)tx*(INn*Bb) + boff;
      #pragma unroll
      for (int kk = 0; kk < 8; ++kk) {
        const int k = kk*8 + kh;
        const float4 wv = *reinterpret_cast<const float4*>(&WX[k][h4]);
        LOAD8(xv, &xin[k*Bb]);
        #pragma unroll
        for (int m = 0; m < 8; ++m) {
          z0i[m]=fmaf(wv.x,xv[m],z0i[m]); z0f[m]=fmaf(wv.y,xv[m],z0f[m]);
          z0g[m]=fmaf(wv.z,xv[m],z0g[m]); z0o[m]=fmaf(wv.w,xv[m],z0o[m]);
        }
      }
    }
    BFLY8(z1i); BFLY8(z1f); BFLY8(z1g); BFLY8(z1o);
    BFLY8(z0i); BFLY8(z0f); BFLY8(z0g); BFLY8(z0o);

    if (p >= 0) {   // cell1(p): all lanes keep redundant c1; kh==0 stores
      float4 oA, oB;
      #pragma unroll
      for (int m = 0; m < 8; ++m) {
        c1[m] = sigm(z1f[m])*c1[m] + sigm(z1i[m])*tanhf(z1g[m]);
        float v = sigm(z1o[m])*tanhf(c1[m]);
        if (m < 4) (&oA.x)[m] = v; else (&oB.x)[m-4] = v;
      }
      if (kh == 0) {
        float* st = P.H1 + (size_t)(p & 1)*SP + (size_t)j*Bb + boff;
        *reinterpret_cast<float4*>(st)     = oA;
        *reinterpret_cast<float4*>(st + 4) = oB;
      }
    }
    if (p < 511) {  // cell0(p+1)
      float4 oA, oB;
      #pragma unroll
      for (int m = 0; m < 8; ++m) {
        c0[m] = sigm(z0f[m])*c0[m] + sigm(z0i[m])*tanhf(z0g[m]);
        float v = sigm(z0o[m])*tanhf(c0[m]);
        if (m < 4) (&oA.x)[m] = v; else (&oB.x)[m-4] = v;
      }
      if (kh == 0) {
        float* st = P.H0 + (size_t)((p+1) & 1)*SP + (size_t)j*Bb + boff;
        *reinterpret_cast<float4*>(st)     = oA;
        *reinterpret_cast<float4*>(st + 4) = oB;
      }
    }
    gridbar_g<128>(P.flags, P.rel, bgen, bh, uw); ++bgen;
  }

  // ---------------- decoder weight load ----------------
  for (int e = tid; e < 512*32; e += TPB) {
    int k = e >> 5, c = e & 31, hh = c >> 3, s = c & 7;
    int unit = 4*uw + hh;
    WA[k][c] = (s < 4) ? P.dWih1[(size_t)(s*Hh + unit)*Hh + k]
                       : P.dWhh1[(size_t)((s-4)*Hh + unit)*Hh + k];
  }
  for (int e = tid; e < 512*16; e += TPB) {
    int k = e >> 4, c = e & 15, hh = c >> 2, g = c & 3;
    WB[k][c] = P.dWhh0[(size_t)(g*Hh + 4*uw + hh)*Hh + k];
  }
  if (tid < 16) {
    int c = tid, hh = c >> 2, g = c & 3;
    WXD[c] = P.dWih0[g*Hh + 4*uw + hh];
  }
  if (tid >= 32 && tid < 64) {
    int c = tid - 32, hh = c >> 3, s = c & 7;
    int unit = 4*uw + hh;
    BS[c] = (s < 4) ? (P.dbih1[s*Hh+unit] + P.dbhh1[s*Hh+unit])
                    : (P.dbih0[(s-4)*Hh+unit] + P.dbhh0[(s-4)*Hh+unit]);
  }
  for (int k = tid; k < Hh; k += TPB) PW[k] = P.projW[k];
  if (tid == 0) PBs = P.projb[0];
  __syncthreads();

  // ---------------- decoder ----------------
  for (int q = 0; q < OUTn; ++q) {
    // ---- phase A: cell0d(q). x(q) = (q==0) ? 0 : proj(h1d(q-1)) ----
    float xq[8] = {0,0,0,0,0,0,0,0};
    if (q > 0) {
      const float* __restrict__ h1p = P.H1 + (size_t)((q+1)&1)*SP + boff;
      float acc[8] = {0,0,0,0,0,0,0,0};
      #pragma unroll 2
      for (int kk = 0; kk < 64; ++kk) {
        const int k = kk*8 + kh;
        float pw = PW[k];
        LOAD8(hp, &h1p[k*Bb]);
        #pragma unroll
        for (int m = 0; m < 8; ++m) acc[m] = fmaf(pw, hp[m], acc[m]);
      }
      BFLY8(acc);
      #pragma unroll
      for (int m = 0; m < 8; ++m) xq[m] = acc[m] + PBs;
      if (uw == 0 && h == 0 && kh == 0) {
        #pragma unroll
        for (int m = 0; m < 8; ++m) P.out[(size_t)(boff + m)*OUTn + (q-1)] = xq[m];
      }
    }
    float zdi[8], zdf[8], zdg[8], zdo[8];
    #pragma unroll
    for (int m = 0; m < 8; ++m) {
      zdi[m] = (kh==0) ? BS[h8+4] : 0.f; zdf[m] = (kh==0) ? BS[h8+5] : 0.f;
      zdg[m] = (kh==0) ? BS[h8+6] : 0.f; zdo[m] = (kh==0) ? BS[h8+7] : 0.f;
    }
    {
      const float* __restrict__ h0p = P.H0 + (size_t)((q+1)&1)*SP + boff;  // h0d(q-1)
      #pragma unroll 2
      for (int kk = 0; kk < 64; ++kk) {
        const int k = kk*8 + kh;
        const float4 wv = *reinterpret_cast<const float4*>(&WB[k][h4]);
        LOAD8(hv, &h0p[k*Bb]);
        #pragma unroll
        for (int m = 0; m < 8; ++m) {
          zdi[m]=fmaf(wv.x,hv[m],zdi[m]); zdf[m]=fmaf(wv.y,hv[m],zdf[m]);
          zdg[m]=fmaf(wv.z,hv[m],zdg[m]); zdo[m]=fmaf(wv.w,hv[m],zdo[m]);
        }
      }
    }
    BFLY8(zdi); BFLY8(zdf); BFLY8(zdg); BFLY8(zdo);
    {
      float4 oA, oB;
      #pragma unroll
      for (int m = 0; m < 8; ++m) {
        float zi = fmaf(WXD[h4+0], xq[m], zdi[m]);
        float zf = fmaf(WXD[h4+1], xq[m], zdf[m]);
        float zg = fmaf(WXD[h4+2], xq[m], zdg[m]);
        float zo = fmaf(WXD[h4+3], xq[m], zdo[m]);
        c0[m] = sigm(zf)*c0[m] + sigm(zi)*tanhf(zg);
        float v = sigm(zo)*tanhf(c0[m]);
        if (m < 4) (&oA.x)[m] = v; else (&oB.x)[m-4] = v;
      }
      if (kh == 0) {
        float* st = P.H0 + (size_t)(q&1)*SP + (size_t)j*Bb + boff;
        *reinterpret_cast<float4*>(st)     = oA;
        *reinterpret_cast<float4*>(st + 4) = oB;
      }
    }
    gridbar_g<128>(P.flags, P.rel, bgen, bh, uw); ++bgen;

    // ---- phase B: cell1d(q) ----
    float yi[8], yf[8], yg[8], yo[8];
    #pragma unroll
    for (int m = 0; m < 8; ++m) {
      yi[m] = (kh==0) ? BS[h8+0] : 0.f; yf[m] = (kh==0) ? BS[h8+1] : 0.f;
      yg[m] = (kh==0) ? BS[h8+2] : 0.f; yo[m] = (kh==0) ? BS[h8+3] : 0.f;
    }
    {
      const float* __restrict__ h0c = P.H0 + (size_t)(q&1)*SP + boff;        // h0d(q)
      const float* __restrict__ h1q = P.H1 + (size_t)((q+1)&1)*SP + boff;    // h1d(q-1)
      #pragma unroll 2
      for (int kk = 0; kk < 64; ++kk) {
        const int k = kk*8 + kh;
        const float4 w1 = *reinterpret_cast<const float4*>(&WA[k][h8]);
        const float4 w2 = *reinterpret_cast<const float4*>(&WA[k][h8+4]);
        LOAD8(av, &h0c[k*Bb]);
        LOAD8(dv, &h1q[k*Bb]);
        #pragma unroll
        for (int m = 0; m < 8; ++m) {
          yi[m]=fmaf(w1.x,av[m],yi[m]); yf[m]=fmaf(w1.y,av[m],yf[m]);
          yg[m]=fmaf(w1.z,av[m],yg[m]); yo[m]=fmaf(w1.w,av[m],yo[m]);
          yi[m]=fmaf(w2.x,dv[m],yi[m]); yf[m]=fmaf(w2.y,dv[m],yf[m]);
          yg[m]=fmaf(w2.z,dv[m],yg[m]); yo[m]=fmaf(w2.w,dv[m],yo[m]);
        }
      }
    }
    BFLY8(yi); BFLY8(yf); BFLY8(yg); BFLY8(yo);
    {
      float4 oA, oB;
      #pragma unroll
      for (int m = 0; m < 8; ++m) {
        c1[m] = sigm(yf[m])*c1[m] + sigm(yi[m])*tanhf(yg[m]);
        float v = sigm(yo[m])*tanhf(c1[m]);
        if (m < 4) (&oA.x)[m] = v; else (&oB.x)[m-4] = v;
      }
      if (kh == 0) {
        float* st = P.H1 + (size_t)(q&1)*SP + (size_t)j*Bb + boff;
        *reinterpret_cast<float4*>(st)     = oA;
        *reinterpret_cast<float4*>(st + 4) = oB;
      }
    }
    gridbar_g<128>(P.flags, P.rel, bgen, bh, uw); ++bgen;
  }

  // ---- final y(OUT-1) ----
  if (uw == 0 && h == 0) {
    const float* __restrict__ h1f = P.H1 + (size_t)((OUTn-1)&1)*SP + boff;
    float acc[8] = {0,0,0,0,0,0,0,0};
    #pragma unroll 2
    for (int kk = 0; kk < 64; ++kk) {
      const int k = kk*8 + kh;
      float pw = PW[k];
      LOAD8(hp, &h1f[k*Bb]);
      #pragma unroll
      for (int m = 0; m < 8; ++m) acc[m] = fmaf(pw, hp[m], acc[m]);
    }
    BFLY8(acc);
    if (kh == 0) {
      #pragma unroll
      for (int m = 0; m < 8; ++m)
        P.out[(size_t)(boff + m)*OUTn + (OUTn-1)] = acc[m] + PBs;
    }
  }
}

extern "C" void kernel_launch(void* const* d_in, const int* in_sizes, int n_in,
                              void* d_out, int out_size, void* d_ws, size_t ws_size,
                              hipStream_t stream) {
  Params P;
  const float* X = (const float*)d_in[0];
  P.Wih0  = (const float*)d_in[1];  P.Whh0  = (const float*)d_in[2];
  P.bih0  = (const float*)d_in[3];  P.bhh0  = (const float*)d_in[4];
  P.Wih1  = (const float*)d_in[5];  P.Whh1  = (const float*)d_in[6];
  P.bih1  = (const float*)d_in[7];  P.bhh1  = (const float*)d_in[8];
  P.dWih0 = (const float*)d_in[9];  P.dWhh0 = (const float*)d_in[10];
  P.dbih0 = (const float*)d_in[11]; P.dbhh0 = (const float*)d_in[12];
  P.dWih1 = (const float*)d_in[13]; P.dWhh1 = (const float*)d_in[14];
  P.dbih1 = (const float*)d_in[15]; P.dbhh1 = (const float*)d_in[16];
  P.projW = (const float*)d_in[17]; P.projb = (const float*)d_in[18];

  float* ws = (float*)d_ws;
  P.flags = (unsigned int*)ws;          // [2][4096] group flags
  P.rel   = (unsigned int*)ws + 8192;   // rel[0], rel[64]
  P.H0  = ws + HDR;                     // [2][H][B]
  P.H1  = ws + HDR + 2*SP;              // [2][H][B]
  float* Xt = ws + HDR + 4*SP;          // [T][IN][B]
  P.Xt  = Xt;
  P.out = (float*)d_out;

  hipMemsetAsync(d_ws, 0, (size_t)(HDR + 4*SP)*sizeof(float), stream);
  hipLaunchKernelGGL(xpose, dim3(Tt), dim3(256), 0, stream, X, Xt);

  void* args[] = { &P };
  hipLaunchCooperativeKernel((void*)lstm_main, dim3(NWG), dim3(TPB), args, 0, stream);
}

// Round 18
// 25881.766 us; speedup vs baseline: 1.0307x; 1.0307x over previous
//
#include <hip/hip_runtime.h>
#include <math.h>

#define Bb   256
#define Tt   512
#define INn  64
#define Hh   512
#define OUTn 96
#define NWG  256
#define TPB  512
#define SP   (Hh*Bb)   // one state plane in floats
#define RSTRIDE 36     // reduction row stride (floats)
#define HDR  12288     // ws header dwords: flags[2][4096] + rel @8192

struct Params {
  const float *Xt;          // [T][IN][B]
  float *H0, *H1;           // [2][H][B] each (ping-pong)
  unsigned int *flags;      // [2 groups][4096] padded arrival flags
  unsigned int *rel;        // rel[g*64] release words
  const float *Wih0,*Whh0,*bih0,*bhh0,*Wih1,*Whh1,*bih1,*bhh1;
  const float *dWih0,*dWhh0,*dbih0,*dbhh0,*dWih1,*dWhh1,*dbih1,*dbhh1;
  const float *projW,*projb;
  float *out;               // [B][OUT]
};

__device__ __forceinline__ float sigm(float x){ return 1.0f/(1.0f + expf(-x)); }

// Group-local barrier (proven R15): two independent 128-WG barriers.
template<int NR>
__device__ __forceinline__ void gridbar_g(unsigned int* flags, unsigned int* rel,
                                          unsigned int g, int bh, int rank) {
  __syncthreads();
  const int tid = threadIdx.x;
  unsigned int* gflags = flags + bh*4096;
  unsigned int* grel   = rel   + bh*64;
  if (rank == 0) {
    if (tid > 0 && tid < NR) {
      while (__hip_atomic_load(&gflags[tid*16], __ATOMIC_RELAXED, __HIP_MEMORY_SCOPE_AGENT) < g)
        __builtin_amdgcn_s_sleep(1);
    }
    __syncthreads();
    if (tid == 0) {
      __threadfence();
      __hip_atomic_store(grel, g, __ATOMIC_RELEASE, __HIP_MEMORY_SCOPE_AGENT);
    }
    __syncthreads();
  } else {
    if (tid == 0) {
      __threadfence();
      __hip_atomic_store(&gflags[rank*16], g, __ATOMIC_RELEASE, __HIP_MEMORY_SCOPE_AGENT);
      while (__hip_atomic_load(grel, __ATOMIC_RELAXED, __HIP_MEMORY_SCOPE_AGENT) < g)
        __builtin_amdgcn_s_sleep(1);
      __threadfence();
    }
    __syncthreads();
  }
}

// Transpose inputs [B][T][IN] -> Xt [T][IN][B]
__global__ void __launch_bounds__(256) xpose(const float* __restrict__ X, float* __restrict__ Xt) {
  __shared__ float tile[64][65];
  const int t = blockIdx.x;
  const int l = threadIdx.x & 63;
  const int r = threadIdx.x >> 6;   // 0..3
  for (int qd = 0; qd < 4; ++qd) {
    #pragma unroll
    for (int rep = 0; rep < 16; ++rep) {
      int bl = rep*4 + r;
      tile[bl][l] = X[(size_t)(qd*64 + bl)*(Tt*INn) + (size_t)t*INn + l];
    }
    __syncthreads();
    #pragma unroll
    for (int rep = 0; rep < 16; ++rep) {
      int i = rep*4 + r;
      Xt[(size_t)t*(INn*Bb) + (size_t)i*Bb + qd*64 + l] = tile[l][i];
    }
    __syncthreads();
  }
}

// R18 = R15 (proven 24.29ms: 4-unit x 128-batch tiling, group-local barrier)
// with the 2-stage chain reduction (3 syncthreads/phase) replaced by R4's
// single-stage 3-buffer reduction (2 syncthreads/phase incl. barrier entry).
// LDS: 141.5KB -> 159.9KB (fits 160KiB, still 1 block/CU).
// WG w: uw=w>>1 owns units 4uw..4uw+3; bh=w&1 owns batches 128bh..+127.
// Thread: bq=tid&31, h=(tid>>5)&3, kh=tid>>7 (0..3).
__global__ void __launch_bounds__(TPB, 2) lstm_main(Params P) {
  __shared__ float WA[512][32];
  __shared__ float WB[512][16];
  __shared__ float WX[64][16];
  __shared__ float BS[32];
  __shared__ float PW[Hh];
  __shared__ float WXD[16];
  __shared__ float PBs;
  __shared__ float RED[3][128][RSTRIDE];   // single-stage: kh 1..3 -> RED[kh-1]

  const int tid = threadIdx.x;
  const int w   = blockIdx.x;
  const int uw  = w >> 1;
  const int bh  = w & 1;
  const int bq  = tid & 31;
  const int h   = (tid >> 5) & 3;
  const int kh  = tid >> 7;
  const int j   = 4*uw + h;
  const int h8  = h*8, h4 = h*4;
  const int slot = h*32 + bq;
  const int boff = 128*bh + 4*bq;
  unsigned int bgen = 1;

  for (int e = tid; e < 512*32; e += TPB) {
    int k = e >> 5, c = e & 31, hh = c >> 3, s = c & 7;
    int unit = 4*uw + hh;
    WA[k][c] = (s < 4) ? P.Wih1[(size_t)(s*Hh + unit)*Hh + k]
                       : P.Whh0[(size_t)((s-4)*Hh + unit)*Hh + k];
  }
  for (int e = tid; e < 512*16; e += TPB) {
    int k = e >> 4, c = e & 15, hh = c >> 2, g = c & 3;
    WB[k][c] = P.Whh1[(size_t)(g*Hh + 4*uw + hh)*Hh + k];
  }
  for (int e = tid; e < 64*16; e += TPB) {
    int k = e >> 4, c = e & 15, hh = c >> 2, g = c & 3;
    WX[k][c] = P.Wih0[(size_t)(g*Hh + 4*uw + hh)*INn + k];
  }
  if (tid < 32) {
    int c = tid, hh = c >> 3, s = c & 7;
    int unit = 4*uw + hh;
    BS[c] = (s < 4) ? (P.bih1[s*Hh+unit] + P.bhh1[s*Hh+unit])
                    : (P.bih0[(s-4)*Hh+unit] + P.bhh0[(s-4)*Hh+unit]);
  }
  __syncthreads();

  float c0[4] = {0,0,0,0}, c1[4] = {0,0,0,0};
  float4 eA_h[4], eA_g[4], eB_h[4], eB_g[4];

#define ENC_LOAD(HB, GB, K0)                                              \
  _Pragma("unroll")                                                       \
  for (int t = 0; t < 4; ++t) {                                           \
    HB[t] = *reinterpret_cast<const float4*>(&h0in[((K0)+t)*Bb]);         \
    GB[t] = *reinterpret_cast<const float4*>(&h1in[((K0)+t)*Bb]);         \
  }
#define ENC_COMPUTE(HB, GB, K0)                                           \
  _Pragma("unroll")                                                       \
  for (int t = 0; t < 4; ++t) {                                           \
    const int k = (K0) + t;                                               \
    const float4 w1 = *reinterpret_cast<const float4*>(&WA[k][h8]);       \
    const float4 w0 = *reinterpret_cast<const float4*>(&WA[k][h8+4]);     \
    const float4 wb = *reinterpret_cast<const float4*>(&WB[k][h4]);       \
    const float* hv = &HB[t].x;                                           \
    const float* gv = &GB[t].x;                                           \
    _Pragma("unroll")                                                     \
    for (int m = 0; m < 4; ++m) {                                         \
      z1i[m]=fmaf(w1.x,hv[m],z1i[m]); z1f[m]=fmaf(w1.y,hv[m],z1f[m]);     \
      z1g[m]=fmaf(w1.z,hv[m],z1g[m]); z1o[m]=fmaf(w1.w,hv[m],z1o[m]);     \
      z0i[m]=fmaf(w0.x,hv[m],z0i[m]); z0f[m]=fmaf(w0.y,hv[m],z0f[m]);     \
      z0g[m]=fmaf(w0.z,hv[m],z0g[m]); z0o[m]=fmaf(w0.w,hv[m],z0o[m]);     \
      z1i[m]=fmaf(wb.x,gv[m],z1i[m]); z1f[m]=fmaf(wb.y,gv[m],z1f[m]);     \
      z1g[m]=fmaf(wb.z,gv[m],z1g[m]); z1o[m]=fmaf(wb.w,gv[m],z1o[m]);     \
    }                                                                     \
  }

  // ---------------- encoder phases ----------------
  for (int p = -1; p <= 511; ++p) {
    float z1i[4], z1f[4], z1g[4], z1o[4];
    float z0i[4], z0f[4], z0g[4], z0o[4];
    #pragma unroll
    for (int m = 0; m < 4; ++m) {
      z1i[m] = (kh==0) ? BS[h8+0] : 0.f; z1f[m] = (kh==0) ? BS[h8+1] : 0.f;
      z1g[m] = (kh==0) ? BS[h8+2] : 0.f; z1o[m] = (kh==0) ? BS[h8+3] : 0.f;
      z0i[m] = (kh==0) ? BS[h8+4] : 0.f; z0f[m] = (kh==0) ? BS[h8+5] : 0.f;
      z0g[m] = (kh==0) ? BS[h8+6] : 0.f; z0o[m] = (kh==0) ? BS[h8+7] : 0.f;
    }
    const float* __restrict__ h0in = P.H0 + (size_t)(p & 1)*SP + boff;
    const float* __restrict__ h1in = P.H1 + (size_t)((p+1) & 1)*SP + boff;
    const int kb = kh*128, ke = kb + 128;

    ENC_LOAD(eA_h, eA_g, kb);
    {
      int tx = (p+1 < Tt) ? (p+1) : (Tt-1);
      const float* __restrict__ xin = P.Xt + (size_t)tx*(INn*Bb) + boff;
      #pragma unroll 4
      for (int k = kh*16; k < kh*16 + 16; ++k) {
        const float4 wv = *reinterpret_cast<const float4*>(&WX[k][h4]);
        const float4 xv4 = *reinterpret_cast<const float4*>(&xin[k*Bb]);
        const float* xv = &xv4.x;
        #pragma unroll
        for (int m = 0; m < 4; ++m) {
          z0i[m]=fmaf(wv.x,xv[m],z0i[m]); z0f[m]=fmaf(wv.y,xv[m],z0f[m]);
          z0g[m]=fmaf(wv.z,xv[m],z0g[m]); z0o[m]=fmaf(wv.w,xv[m],z0o[m]);
        }
      }
    }
    for (int kk = kb; kk < ke; kk += 8) {
      ENC_LOAD(eB_h, eB_g, kk+4);
      ENC_COMPUTE(eA_h, eA_g, kk);
      const int kn = (kk+8 < ke) ? (kk+8) : kb;
      ENC_LOAD(eA_h, eA_g, kn);
      ENC_COMPUTE(eB_h, eB_g, kk+4);
    }

    // single-stage 3-buffer reduction (R4 pattern)
    if (kh) {
      float* r = &RED[kh-1][slot][0];
      *reinterpret_cast<float4*>(&r[ 0]) = make_float4(z1i[0],z1i[1],z1i[2],z1i[3]);
      *reinterpret_cast<float4*>(&r[ 4]) = make_float4(z1f[0],z1f[1],z1f[2],z1f[3]);
      *reinterpret_cast<float4*>(&r[ 8]) = make_float4(z1g[0],z1g[1],z1g[2],z1g[3]);
      *reinterpret_cast<float4*>(&r[12]) = make_float4(z1o[0],z1o[1],z1o[2],z1o[3]);
      *reinterpret_cast<float4*>(&r[16]) = make_float4(z0i[0],z0i[1],z0i[2],z0i[3]);
      *reinterpret_cast<float4*>(&r[20]) = make_float4(z0f[0],z0f[1],z0f[2],z0f[3]);
      *reinterpret_cast<float4*>(&r[24]) = make_float4(z0g[0],z0g[1],z0g[2],z0g[3]);
      *reinterpret_cast<float4*>(&r[28]) = make_float4(z0o[0],z0o[1],z0o[2],z0o[3]);
    }
    __syncthreads();
    if (kh == 0) {
      #pragma unroll
      for (int t = 0; t < 3; ++t) {
        const float* r = &RED[t][slot][0];
        #pragma unroll
        for (int m = 0; m < 4; ++m) {
          z1i[m]+=r[ 0+m]; z1f[m]+=r[ 4+m]; z1g[m]+=r[ 8+m]; z1o[m]+=r[12+m];
          z0i[m]+=r[16+m]; z0f[m]+=r[20+m]; z0g[m]+=r[24+m]; z0o[m]+=r[28+m];
        }
      }
      if (p >= 0) {
        float* st = P.H1 + (size_t)(p & 1)*SP + (size_t)j*Bb + boff;
        float4 o; float* ov = &o.x;
        #pragma unroll
        for (int m = 0; m < 4; ++m) {
          c1[m] = sigm(z1f[m])*c1[m] + sigm(z1i[m])*tanhf(z1g[m]);
          ov[m] = sigm(z1o[m])*tanhf(c1[m]);
        }
        *reinterpret_cast<float4*>(st) = o;
      }
      if (p < 511) {
        float* st = P.H0 + (size_t)((p+1) & 1)*SP + (size_t)j*Bb + boff;
        float4 o; float* ov = &o.x;
        #pragma unroll
        for (int m = 0; m < 4; ++m) {
          c0[m] = sigm(z0f[m])*c0[m] + sigm(z0i[m])*tanhf(z0g[m]);
          ov[m] = sigm(z0o[m])*tanhf(c0[m]);
        }
        *reinterpret_cast<float4*>(st) = o;
      }
    }
    gridbar_g<128>(P.flags, P.rel, bgen, bh, uw); ++bgen;
  }

  // ---------------- decoder weight load ----------------
  for (int e = tid; e < 512*32; e += TPB) {
    int k = e >> 5, c = e & 31, hh = c >> 3, s = c & 7;
    int unit = 4*uw + hh;
    WA[k][c] = (s < 4) ? P.dWih1[(size_t)(s*Hh + unit)*Hh + k]
                       : P.dWhh1[(size_t)((s-4)*Hh + unit)*Hh + k];
  }
  for (int e = tid; e < 512*16; e += TPB) {
    int k = e >> 4, c = e & 15, hh = c >> 2, g = c & 3;
    WB[k][c] = P.dWhh0[(size_t)(g*Hh + 4*uw + hh)*Hh + k];
  }
  if (tid < 16) {
    int c = tid, hh = c >> 2, g = c & 3;
    WXD[c] = P.dWih0[g*Hh + 4*uw + hh];
  }
  if (tid >= 32 && tid < 64) {
    int c = tid - 32, hh = c >> 3, s = c & 7;
    int unit = 4*uw + hh;
    BS[c] = (s < 4) ? (P.dbih1[s*Hh+unit] + P.dbhh1[s*Hh+unit])
                    : (P.dbih0[(s-4)*Hh+unit] + P.dbhh0[(s-4)*Hh+unit]);
  }
  for (int k = tid; k < Hh; k += TPB) PW[k] = P.projW[k];
  if (tid == 0) PBs = P.projb[0];
  __syncthreads();

  // ---------------- decoder ----------------
  for (int q = 0; q < OUTn; ++q) {
    // ---- phase A: cell0d(q). x(q) = (q==0) ? 0 : proj(h1d(q-1)) ----
    float xq[4];
    #pragma unroll
    for (int m = 0; m < 4; ++m) xq[m] = (kh==0 && q>0) ? PBs : 0.f;
    if (q > 0) {
      const float* __restrict__ h1p = P.H1 + (size_t)((q+1)&1)*SP + boff;
      const int kb = kh*128, ke = kb + 128;
      #pragma unroll 4
      for (int k = kb; k < ke; ++k) {
        float pw = PW[k];
        const float4 hp4 = *reinterpret_cast<const float4*>(&h1p[k*Bb]);
        const float* hp = &hp4.x;
        #pragma unroll
        for (int m = 0; m < 4; ++m) xq[m] = fmaf(pw, hp[m], xq[m]);
      }
    }
    float zd[4][4];
    #pragma unroll
    for (int g = 0; g < 4; ++g)
      #pragma unroll
      for (int m = 0; m < 4; ++m)
        zd[g][m] = (kh==0) ? BS[h8+4+g] : 0.f;
    {
      const float* __restrict__ h0p = P.H0 + (size_t)((q+1)&1)*SP + boff;
      const int kb = kh*128, ke = kb + 128;
      #pragma unroll 4
      for (int k = kb; k < ke; ++k) {
        const float4 wv = *reinterpret_cast<const float4*>(&WB[k][h4]);
        const float4 hv4 = *reinterpret_cast<const float4*>(&h0p[k*Bb]);
        const float* hv = &hv4.x;
        #pragma unroll
        for (int m = 0; m < 4; ++m) {
          zd[0][m]=fmaf(wv.x,hv[m],zd[0][m]); zd[1][m]=fmaf(wv.y,hv[m],zd[1][m]);
          zd[2][m]=fmaf(wv.z,hv[m],zd[2][m]); zd[3][m]=fmaf(wv.w,hv[m],zd[3][m]);
        }
      }
    }
    if (kh) {
      float* r = &RED[kh-1][slot][0];
      #pragma unroll
      for (int g = 0; g < 4; ++g)
        *reinterpret_cast<float4*>(&r[g*4]) = make_float4(zd[g][0],zd[g][1],zd[g][2],zd[g][3]);
      *reinterpret_cast<float4*>(&r[16]) = make_float4(xq[0],xq[1],xq[2],xq[3]);
    }
    __syncthreads();
    if (kh == 0) {
      #pragma unroll
      for (int t = 0; t < 3; ++t) {
        const float* r = &RED[t][slot][0];
        #pragma unroll
        for (int g = 0; g < 4; ++g) {
          const float4 v = *reinterpret_cast<const float4*>(&r[g*4]);
          zd[g][0]+=v.x; zd[g][1]+=v.y; zd[g][2]+=v.z; zd[g][3]+=v.w;
        }
        const float4 v = *reinterpret_cast<const float4*>(&r[16]);
        xq[0]+=v.x; xq[1]+=v.y; xq[2]+=v.z; xq[3]+=v.w;
      }
      if (uw == 0 && h == 0 && q > 0) {
        #pragma unroll
        for (int m = 0; m < 4; ++m) P.out[(size_t)(boff + m)*OUTn + (q-1)] = xq[m];
      }
      float* st = P.H0 + (size_t)(q&1)*SP + (size_t)j*Bb + boff;
      float4 o; float* ov = &o.x;
      #pragma unroll
      for (int m = 0; m < 4; ++m) {
        float zi = fmaf(WXD[h4+0], xq[m], zd[0][m]);
        float zf = fmaf(WXD[h4+1], xq[m], zd[1][m]);
        float zg = fmaf(WXD[h4+2], xq[m], zd[2][m]);
        float zo = fmaf(WXD[h4+3], xq[m], zd[3][m]);
        c0[m] = sigm(zf)*c0[m] + sigm(zi)*tanhf(zg);
        ov[m] = sigm(zo)*tanhf(c0[m]);
      }
      *reinterpret_cast<float4*>(st) = o;
    }
    gridbar_g<128>(P.flags, P.rel, bgen, bh, uw); ++bgen;

    // ---- phase B: cell1d(q) ----
    float y[4][4];
    #pragma unroll
    for (int g = 0; g < 4; ++g)
      #pragma unroll
      for (int m = 0; m < 4; ++m)
        y[g][m] = (kh==0) ? BS[h8+g] : 0.f;
    {
      const float* __restrict__ h0c = P.H0 + (size_t)(q&1)*SP + boff;
      const float* __restrict__ h1q = P.H1 + (size_t)((q+1)&1)*SP + boff;
      const int kb = kh*128, ke = kb + 128;
      #pragma unroll 4
      for (int k = kb; k < ke; ++k) {
        const float4 w1 = *reinterpret_cast<const float4*>(&WA[k][h8]);
        const float4 w2 = *reinterpret_cast<const float4*>(&WA[k][h8+4]);
        const float4 av4 = *reinterpret_cast<const float4*>(&h0c[k*Bb]);
        const float4 dv4 = *reinterpret_cast<const float4*>(&h1q[k*Bb]);
        const float* av = &av4.x;
        const float* dv = &dv4.x;
        #pragma unroll
        for (int m = 0; m < 4; ++m) {
          y[0][m]=fmaf(w1.x,av[m],y[0][m]); y[1][m]=fmaf(w1.y,av[m],y[1][m]);
          y[2][m]=fmaf(w1.z,av[m],y[2][m]); y[3][m]=fmaf(w1.w,av[m],y[3][m]);
          y[0][m]=fmaf(w2.x,dv[m],y[0][m]); y[1][m]=fmaf(w2.y,dv[m],y[1][m]);
          y[2][m]=fmaf(w2.z,dv[m],y[2][m]); y[3][m]=fmaf(w2.w,dv[m],y[3][m]);
        }
      }
    }
    if (kh) {
      float* r = &RED[kh-1][slot][0];
      #pragma unroll
      for (int g = 0; g < 4; ++g)
        *reinterpret_cast<float4*>(&r[g*4]) = make_float4(y[g][0],y[g][1],y[g][2],y[g][3]);
    }
    __syncthreads();
    if (kh == 0) {
      #pragma unroll
      for (int t = 0; t < 3; ++t) {
        const float* r = &RED[t][slot][0];
        #pragma unroll
        for (int g = 0; g < 4; ++g) {
          const float4 v = *reinterpret_cast<const float4*>(&r[g*4]);
          y[g][0]+=v.x; y[g][1]+=v.y; y[g][2]+=v.z; y[g][3]+=v.w;
        }
      }
      float* st = P.H1 + (size_t)(q&1)*SP + (size_t)j*Bb + boff;
      float4 o; float* ov = &o.x;
      #pragma unroll
      for (int m = 0; m < 4; ++m) {
        c1[m] = sigm(y[1][m])*c1[m] + sigm(y[0][m])*tanhf(y[2][m]);
        ov[m] = sigm(y[3][m])*tanhf(c1[m]);
      }
      *reinterpret_cast<float4*>(st) = o;
    }
    gridbar_g<128>(P.flags, P.rel, bgen, bh, uw); ++bgen;
  }

  // ---- final y(OUT-1) ----
  if (kh == 0 && uw == 0 && h == 0) {
    const float* __restrict__ h1f = P.H1 + (size_t)((OUTn-1)&1)*SP + boff;
    float acc[4] = {PBs, PBs, PBs, PBs};
    #pragma unroll 4
    for (int k = 0; k < Hh; ++k) {
      float pw = PW[k];
      const float4 hp4 = *reinterpret_cast<const float4*>(&h1f[k*Bb]);
      const float* hp = &hp4.x;
      #pragma unroll
      for (int m = 0; m < 4; ++m) acc[m] = fmaf(pw, hp[m], acc[m]);
    }
    #pragma unroll
    for (int m = 0; m < 4; ++m) P.out[(size_t)(boff + m)*OUTn + (OUTn-1)] = acc[m];
  }
}

extern "C" void kernel_launch(void* const* d_in, const int* in_sizes, int n_in,
                              void* d_out, int out_size, void* d_ws, size_t ws_size,
                              hipStream_t stream) {
  Params P;
  const float* X = (const float*)d_in[0];
  P.Wih0  = (const float*)d_in[1];  P.Whh0  = (const float*)d_in[2];
  P.bih0  = (const float*)d_in[3];  P.bhh0  = (const float*)d_in[4];
  P.Wih1  = (const float*)d_in[5];  P.Whh1  = (const float*)d_in[6];
  P.bih1  = (const float*)d_in[7];  P.bhh1  = (const float*)d_in[8];
  P.dWih0 = (const float*)d_in[9];  P.dWhh0 = (const float*)d_in[10];
  P.dbih0 = (const float*)d_in[11]; P.dbhh0 = (const float*)d_in[12];
  P.dWih1 = (const float*)d_in[13]; P.dWhh1 = (const float*)d_in[14];
  P.dbih1 = (const float*)d_in[15]; P.dbhh1 = (const float*)d_in[16];
  P.projW = (const float*)d_in[17]; P.projb = (const float*)d_in[18];

  float* ws = (float*)d_ws;
  P.flags = (unsigned int*)ws;          // [2][4096] group flags
  P.rel   = (unsigned int*)ws + 8192;   // rel[0], rel[64]
  P.H0  = ws + HDR;                     // [2][H][B]
  P.H1  = ws + HDR + 2*SP;              // [2][H][B]
  float* Xt = ws + HDR + 4*SP;          // [T][IN][B]
  P.Xt  = Xt;
  P.out = (float*)d_out;

  hipMemsetAsync(d_ws, 0, (size_t)(HDR + 4*SP)*sizeof(float), stream);
  hipLaunchKernelGGL(xpose, dim3(Tt), dim3(256), 0, stream, X, Xt);

  void* args[] = { &P };
  hipLaunchCooperativeKernel((void*)lstm_main, dim3(NWG), dim3(TPB), args, 0, stream);
}

// Round 19
// 24166.693 us; speedup vs baseline: 1.1039x; 1.0710x over previous
//
#include <hip/hip_runtime.h>
#include <math.h>

#define Bb   256
#define Tt   512
#define INn  64
#define Hh   512
#define OUTn 96
#define NWG  256
#define TPB  512
#define SP   (Hh*Bb)   // one state plane in floats
#define RSTRIDE 36     // reduction row stride (floats)
#define HDR  12288     // ws header dwords: flags[2][4096] + rel words @8192

struct Params {
  const float *Xt;          // [T][IN][B]
  float *H0, *H1;           // [2][H][B] each (ping-pong)
  unsigned int *flags;      // [2 groups][4096] padded arrival flags
  unsigned int *rel;        // rel[g*64] release words (256B apart)
  const float *Wih0,*Whh0,*bih0,*bhh0,*Wih1,*Whh1,*bih1,*bhh1;
  const float *dWih0,*dWhh0,*dbih0,*dbhh0,*dWih1,*dWhh1,*dbih1,*dbhh1;
  const float *projW,*projb;
  float *out;               // [B][OUT]
};

__device__ __forceinline__ float sigm(float x){ return 1.0f/(1.0f + expf(-x)); }

// Group-local barrier: two independent 128-WG barriers (batch halves are
// fully independent in the LSTM; only read-only weights/Xt are shared).
// Group g: members are blocks with (w&1)==g, member rank uw = w>>1 (0..127).
// Checker = rank 0 (blocks 0 and 1). Same fence pattern as proven R4-R14.
__device__ __forceinline__ void gridbar_g(unsigned int* flags, unsigned int* rel,
                                          unsigned int g, int bh, int uw) {
  __syncthreads();
  const int tid = threadIdx.x;
  unsigned int* gflags = flags + bh*4096;
  unsigned int* grel   = rel   + bh*64;
  if (uw == 0) {
    if (tid > 0 && tid < 128) {
      while (__hip_atomic_load(&gflags[tid*16], __ATOMIC_RELAXED, __HIP_MEMORY_SCOPE_AGENT) < g)
        __builtin_amdgcn_s_sleep(1);
    }
    __syncthreads();
    if (tid == 0) {
      __threadfence();
      __hip_atomic_store(grel, g, __ATOMIC_RELEASE, __HIP_MEMORY_SCOPE_AGENT);
    }
    __syncthreads();
  } else {
    if (tid == 0) {
      __threadfence();
      __hip_atomic_store(&gflags[uw*16], g, __ATOMIC_RELEASE, __HIP_MEMORY_SCOPE_AGENT);
      while (__hip_atomic_load(grel, __ATOMIC_RELAXED, __HIP_MEMORY_SCOPE_AGENT) < g)
        __builtin_amdgcn_s_sleep(1);
      __threadfence();
    }
    __syncthreads();
  }
}

// Transpose inputs [B][T][IN] -> Xt [T][IN][B]
__global__ void __launch_bounds__(256) xpose(const float* __restrict__ X, float* __restrict__ Xt) {
  __shared__ float tile[64][65];
  const int t = blockIdx.x;
  const int l = threadIdx.x & 63;
  const int r = threadIdx.x >> 6;   // 0..3
  for (int qd = 0; qd < 4; ++qd) {
    #pragma unroll
    for (int rep = 0; rep < 16; ++rep) {
      int bl = rep*4 + r;
      tile[bl][l] = X[(size_t)(qd*64 + bl)*(Tt*INn) + (size_t)t*INn + l];
    }
    __syncthreads();
    #pragma unroll
    for (int rep = 0; rep < 16; ++rep) {
      int i = rep*4 + r;
      Xt[(size_t)t*(INn*Bb) + (size_t)i*Bb + qd*64 + l] = tile[l][i];
    }
    __syncthreads();
  }
}

// Persistent cooperative kernel — R12 structure with GROUP-LOCAL barriers
// (R15, best proven: 24.29ms): the two batch halves never wait on each other.
// STRUCTURAL FLOOR NOTE: 705 serially-dependent grid-wide phases; measured
// residue ~22us/phase is exchange-visibility + straggler jitter, invariant
// across occupancy/ILP/traffic/LDS levers (R10-R18). VALU floor ~12us/phase.
// WG w: uw = w>>1 owns units 4uw..4uw+3; bh = w&1 owns batches 128bh..+127.
// Thread: bq = tid&31 (batch quad), h = (tid>>5)&3 (unit), kh = tid>>7.
__global__ void __launch_bounds__(TPB, 2) lstm_main(Params P) {
  __shared__ float WA[512][32];
  __shared__ float WB[512][16];
  __shared__ float WX[64][16];
  __shared__ float BS[32];
  __shared__ float PW[Hh];
  __shared__ float WXD[16];
  __shared__ float PBs;
  __shared__ float RED[2][128][RSTRIDE];

  const int tid = threadIdx.x;
  const int w   = blockIdx.x;
  const int uw  = w >> 1;
  const int bh  = w & 1;
  const int bq  = tid & 31;
  const int h   = (tid >> 5) & 3;
  const int kh  = tid >> 7;
  const int j   = 4*uw + h;
  const int h8  = h*8, h4 = h*4;
  const int slot = h*32 + bq;
  const int boff = 128*bh + 4*bq;
  unsigned int bgen = 1;

  for (int e = tid; e < 512*32; e += TPB) {
    int k = e >> 5, c = e & 31, hh = c >> 3, s = c & 7;
    int unit = 4*uw + hh;
    WA[k][c] = (s < 4) ? P.Wih1[(size_t)(s*Hh + unit)*Hh + k]
                       : P.Whh0[(size_t)((s-4)*Hh + unit)*Hh + k];
  }
  for (int e = tid; e < 512*16; e += TPB) {
    int k = e >> 4, c = e & 15, hh = c >> 2, g = c & 3;
    WB[k][c] = P.Whh1[(size_t)(g*Hh + 4*uw + hh)*Hh + k];
  }
  for (int e = tid; e < 64*16; e += TPB) {
    int k = e >> 4, c = e & 15, hh = c >> 2, g = c & 3;
    WX[k][c] = P.Wih0[(size_t)(g*Hh + 4*uw + hh)*INn + k];
  }
  if (tid < 32) {
    int c = tid, hh = c >> 3, s = c & 7;
    int unit = 4*uw + hh;
    BS[c] = (s < 4) ? (P.bih1[s*Hh+unit] + P.bhh1[s*Hh+unit])
                    : (P.bih0[(s-4)*Hh+unit] + P.bhh0[(s-4)*Hh+unit]);
  }
  __syncthreads();

  float c0[4] = {0,0,0,0}, c1[4] = {0,0,0,0};
  float4 eA_h[4], eA_g[4], eB_h[4], eB_g[4];

#define ENC_LOAD(HB, GB, K0)                                              \
  _Pragma("unroll")                                                       \
  for (int t = 0; t < 4; ++t) {                                           \
    HB[t] = *reinterpret_cast<const float4*>(&h0in[((K0)+t)*Bb]);         \
    GB[t] = *reinterpret_cast<const float4*>(&h1in[((K0)+t)*Bb]);         \
  }
#define ENC_COMPUTE(HB, GB, K0)                                           \
  _Pragma("unroll")                                                       \
  for (int t = 0; t < 4; ++t) {                                           \
    const int k = (K0) + t;                                               \
    const float4 w1 = *reinterpret_cast<const float4*>(&WA[k][h8]);       \
    const float4 w0 = *reinterpret_cast<const float4*>(&WA[k][h8+4]);     \
    const float4 wb = *reinterpret_cast<const float4*>(&WB[k][h4]);       \
    const float* hv = &HB[t].x;                                           \
    const float* gv = &GB[t].x;                                           \
    _Pragma("unroll")                                                     \
    for (int m = 0; m < 4; ++m) {                                         \
      z1i[m]=fmaf(w1.x,hv[m],z1i[m]); z1f[m]=fmaf(w1.y,hv[m],z1f[m]);     \
      z1g[m]=fmaf(w1.z,hv[m],z1g[m]); z1o[m]=fmaf(w1.w,hv[m],z1o[m]);     \
      z0i[m]=fmaf(w0.x,hv[m],z0i[m]); z0f[m]=fmaf(w0.y,hv[m],z0f[m]);     \
      z0g[m]=fmaf(w0.z,hv[m],z0g[m]); z0o[m]=fmaf(w0.w,hv[m],z0o[m]);     \
      z1i[m]=fmaf(wb.x,gv[m],z1i[m]); z1f[m]=fmaf(wb.y,gv[m],z1f[m]);     \
      z1g[m]=fmaf(wb.z,gv[m],z1g[m]); z1o[m]=fmaf(wb.w,gv[m],z1o[m]);     \
    }                                                                     \
  }

  // ---------------- encoder phases ----------------
  for (int p = -1; p <= 511; ++p) {
    float z1i[4], z1f[4], z1g[4], z1o[4];
    float z0i[4], z0f[4], z0g[4], z0o[4];
    #pragma unroll
    for (int m = 0; m < 4; ++m) {
      z1i[m] = (kh==0) ? BS[h8+0] : 0.f; z1f[m] = (kh==0) ? BS[h8+1] : 0.f;
      z1g[m] = (kh==0) ? BS[h8+2] : 0.f; z1o[m] = (kh==0) ? BS[h8+3] : 0.f;
      z0i[m] = (kh==0) ? BS[h8+4] : 0.f; z0f[m] = (kh==0) ? BS[h8+5] : 0.f;
      z0g[m] = (kh==0) ? BS[h8+6] : 0.f; z0o[m] = (kh==0) ? BS[h8+7] : 0.f;
    }
    const float* __restrict__ h0in = P.H0 + (size_t)(p & 1)*SP + boff;
    const float* __restrict__ h1in = P.H1 + (size_t)((p+1) & 1)*SP + boff;
    const int kb = kh*128, ke = kb + 128;

    ENC_LOAD(eA_h, eA_g, kb);
    {
      int tx = (p+1 < Tt) ? (p+1) : (Tt-1);
      const float* __restrict__ xin = P.Xt + (size_t)tx*(INn*Bb) + boff;
      #pragma unroll 4
      for (int k = kh*16; k < kh*16 + 16; ++k) {
        const float4 wv = *reinterpret_cast<const float4*>(&WX[k][h4]);
        const float4 xv4 = *reinterpret_cast<const float4*>(&xin[k*Bb]);
        const float* xv = &xv4.x;
        #pragma unroll
        for (int m = 0; m < 4; ++m) {
          z0i[m]=fmaf(wv.x,xv[m],z0i[m]); z0f[m]=fmaf(wv.y,xv[m],z0f[m]);
          z0g[m]=fmaf(wv.z,xv[m],z0g[m]); z0o[m]=fmaf(wv.w,xv[m],z0o[m]);
        }
      }
    }
    for (int kk = kb; kk < ke; kk += 8) {
      ENC_LOAD(eB_h, eB_g, kk+4);
      ENC_COMPUTE(eA_h, eA_g, kk);
      const int kn = (kk+8 < ke) ? (kk+8) : kb;
      ENC_LOAD(eA_h, eA_g, kn);
      ENC_COMPUTE(eB_h, eB_g, kk+4);
    }

    if (kh >= 2) {
      float* r = &RED[kh-2][slot][0];
      *reinterpret_cast<float4*>(&r[ 0]) = make_float4(z1i[0],z1i[1],z1i[2],z1i[3]);
      *reinterpret_cast<float4*>(&r[ 4]) = make_float4(z1f[0],z1f[1],z1f[2],z1f[3]);
      *reinterpret_cast<float4*>(&r[ 8]) = make_float4(z1g[0],z1g[1],z1g[2],z1g[3]);
      *reinterpret_cast<float4*>(&r[12]) = make_float4(z1o[0],z1o[1],z1o[2],z1o[3]);
      *reinterpret_cast<float4*>(&r[16]) = make_float4(z0i[0],z0i[1],z0i[2],z0i[3]);
      *reinterpret_cast<float4*>(&r[20]) = make_float4(z0f[0],z0f[1],z0f[2],z0f[3]);
      *reinterpret_cast<float4*>(&r[24]) = make_float4(z0g[0],z0g[1],z0g[2],z0g[3]);
      *reinterpret_cast<float4*>(&r[28]) = make_float4(z0o[0],z0o[1],z0o[2],z0o[3]);
    }
    __syncthreads();
    if (kh < 2) {
      float* r = &RED[kh][slot][0];
      {
        const float* rr = r;
        #pragma unroll
        for (int m = 0; m < 4; ++m) {
          z1i[m]+=rr[ 0+m]; z1f[m]+=rr[ 4+m]; z1g[m]+=rr[ 8+m]; z1o[m]+=rr[12+m];
          z0i[m]+=rr[16+m]; z0f[m]+=rr[20+m]; z0g[m]+=rr[24+m]; z0o[m]+=rr[28+m];
        }
      }
      if (kh == 1) {
        *reinterpret_cast<float4*>(&r[ 0]) = make_float4(z1i[0],z1i[1],z1i[2],z1i[3]);
        *reinterpret_cast<float4*>(&r[ 4]) = make_float4(z1f[0],z1f[1],z1f[2],z1f[3]);
        *reinterpret_cast<float4*>(&r[ 8]) = make_float4(z1g[0],z1g[1],z1g[2],z1g[3]);
        *reinterpret_cast<float4*>(&r[12]) = make_float4(z1o[0],z1o[1],z1o[2],z1o[3]);
        *reinterpret_cast<float4*>(&r[16]) = make_float4(z0i[0],z0i[1],z0i[2],z0i[3]);
        *reinterpret_cast<float4*>(&r[20]) = make_float4(z0f[0],z0f[1],z0f[2],z0f[3]);
        *reinterpret_cast<float4*>(&r[24]) = make_float4(z0g[0],z0g[1],z0g[2],z0g[3]);
        *reinterpret_cast<float4*>(&r[28]) = make_float4(z0o[0],z0o[1],z0o[2],z0o[3]);
      }
    }
    __syncthreads();
    if (kh == 0) {
      const float* rr = &RED[1][slot][0];
      #pragma unroll
      for (int m = 0; m < 4; ++m) {
        z1i[m]+=rr[ 0+m]; z1f[m]+=rr[ 4+m]; z1g[m]+=rr[ 8+m]; z1o[m]+=rr[12+m];
        z0i[m]+=rr[16+m]; z0f[m]+=rr[20+m]; z0g[m]+=rr[24+m]; z0o[m]+=rr[28+m];
      }
      if (p >= 0) {
        float* st = P.H1 + (size_t)(p & 1)*SP + (size_t)j*Bb + boff;
        float4 o; float* ov = &o.x;
        #pragma unroll
        for (int m = 0; m < 4; ++m) {
          c1[m] = sigm(z1f[m])*c1[m] + sigm(z1i[m])*tanhf(z1g[m]);
          ov[m] = sigm(z1o[m])*tanhf(c1[m]);
        }
        *reinterpret_cast<float4*>(st) = o;
      }
      if (p < 511) {
        float* st = P.H0 + (size_t)((p+1) & 1)*SP + (size_t)j*Bb + boff;
        float4 o; float* ov = &o.x;
        #pragma unroll
        for (int m = 0; m < 4; ++m) {
          c0[m] = sigm(z0f[m])*c0[m] + sigm(z0i[m])*tanhf(z0g[m]);
          ov[m] = sigm(z0o[m])*tanhf(c0[m]);
        }
        *reinterpret_cast<float4*>(st) = o;
      }
    }
    gridbar_g(P.flags, P.rel, bgen, bh, uw); ++bgen;
  }

  // ---------------- decoder weight load ----------------
  for (int e = tid; e < 512*32; e += TPB) {
    int k = e >> 5, c = e & 31, hh = c >> 3, s = c & 7;
    int unit = 4*uw + hh;
    WA[k][c] = (s < 4) ? P.dWih1[(size_t)(s*Hh + unit)*Hh + k]
                       : P.dWhh1[(size_t)((s-4)*Hh + unit)*Hh + k];
  }
  for (int e = tid; e < 512*16; e += TPB) {
    int k = e >> 4, c = e & 15, hh = c >> 2, g = c & 3;
    WB[k][c] = P.dWhh0[(size_t)(g*Hh + 4*uw + hh)*Hh + k];
  }
  if (tid < 16) {
    int c = tid, hh = c >> 2, g = c & 3;
    WXD[c] = P.dWih0[g*Hh + 4*uw + hh];
  }
  if (tid >= 32 && tid < 64) {
    int c = tid - 32, hh = c >> 3, s = c & 7;
    int unit = 4*uw + hh;
    BS[c] = (s < 4) ? (P.dbih1[s*Hh+unit] + P.dbhh1[s*Hh+unit])
                    : (P.dbih0[(s-4)*Hh+unit] + P.dbhh0[(s-4)*Hh+unit]);
  }
  for (int k = tid; k < Hh; k += TPB) PW[k] = P.projW[k];
  if (tid == 0) PBs = P.projb[0];
  __syncthreads();

  // ---------------- decoder ----------------
  for (int q = 0; q < OUTn; ++q) {
    float xq[4];
    #pragma unroll
    for (int m = 0; m < 4; ++m) xq[m] = (kh==0 && q>0) ? PBs : 0.f;
    if (q > 0) {
      const float* __restrict__ h1p = P.H1 + (size_t)((q+1)&1)*SP + boff;
      const int kb = kh*128, ke = kb + 128;
      #pragma unroll 4
      for (int k = kb; k < ke; ++k) {
        float pw = PW[k];
        const float4 hp4 = *reinterpret_cast<const float4*>(&h1p[k*Bb]);
        const float* hp = &hp4.x;
        #pragma unroll
        for (int m = 0; m < 4; ++m) xq[m] = fmaf(pw, hp[m], xq[m]);
      }
    }
    float zd[4][4];
    #pragma unroll
    for (int g = 0; g < 4; ++g)
      #pragma unroll
      for (int m = 0; m < 4; ++m)
        zd[g][m] = (kh==0) ? BS[h8+4+g] : 0.f;
    {
      const float* __restrict__ h0p = P.H0 + (size_t)((q+1)&1)*SP + boff;
      const int kb = kh*128, ke = kb + 128;
      #pragma unroll 4
      for (int k = kb; k < ke; ++k) {
        const float4 wv = *reinterpret_cast<const float4*>(&WB[k][h4]);
        const float4 hv4 = *reinterpret_cast<const float4*>(&h0p[k*Bb]);
        const float* hv = &hv4.x;
        #pragma unroll
        for (int m = 0; m < 4; ++m) {
          zd[0][m]=fmaf(wv.x,hv[m],zd[0][m]); zd[1][m]=fmaf(wv.y,hv[m],zd[1][m]);
          zd[2][m]=fmaf(wv.z,hv[m],zd[2][m]); zd[3][m]=fmaf(wv.w,hv[m],zd[3][m]);
        }
      }
    }
    if (kh >= 2) {
      float* r = &RED[kh-2][slot][0];
      #pragma unroll
      for (int g = 0; g < 4; ++g)
        *reinterpret_cast<float4*>(&r[g*4]) = make_float4(zd[g][0],zd[g][1],zd[g][2],zd[g][3]);
      *reinterpret_cast<float4*>(&r[16]) = make_float4(xq[0],xq[1],xq[2],xq[3]);
    }
    __syncthreads();
    if (kh < 2) {
      float* r = &RED[kh][slot][0];
      #pragma unroll
      for (int g = 0; g < 4; ++g) {
        const float4 v = *reinterpret_cast<const float4*>(&r[g*4]);
        zd[g][0]+=v.x; zd[g][1]+=v.y; zd[g][2]+=v.z; zd[g][3]+=v.w;
      }
      {
        const float4 v = *reinterpret_cast<const float4*>(&r[16]);
        xq[0]+=v.x; xq[1]+=v.y; xq[2]+=v.z; xq[3]+=v.w;
      }
      if (kh == 1) {
        #pragma unroll
        for (int g = 0; g < 4; ++g)
          *reinterpret_cast<float4*>(&r[g*4]) = make_float4(zd[g][0],zd[g][1],zd[g][2],zd[g][3]);
        *reinterpret_cast<float4*>(&r[16]) = make_float4(xq[0],xq[1],xq[2],xq[3]);
      }
    }
    __syncthreads();
    if (kh == 0) {
      const float* r = &RED[1][slot][0];
      #pragma unroll
      for (int g = 0; g < 4; ++g) {
        const float4 v = *reinterpret_cast<const float4*>(&r[g*4]);
        zd[g][0]+=v.x; zd[g][1]+=v.y; zd[g][2]+=v.z; zd[g][3]+=v.w;
      }
      {
        const float4 v = *reinterpret_cast<const float4*>(&r[16]);
        xq[0]+=v.x; xq[1]+=v.y; xq[2]+=v.z; xq[3]+=v.w;
      }
      if (uw == 0 && h == 0 && q > 0) {
        #pragma unroll
        for (int m = 0; m < 4; ++m) P.out[(size_t)(boff + m)*OUTn + (q-1)] = xq[m];
      }
      float* st = P.H0 + (size_t)(q&1)*SP + (size_t)j*Bb + boff;
      float4 o; float* ov = &o.x;
      #pragma unroll
      for (int m = 0; m < 4; ++m) {
        float zi = fmaf(WXD[h4+0], xq[m], zd[0][m]);
        float zf = fmaf(WXD[h4+1], xq[m], zd[1][m]);
        float zg = fmaf(WXD[h4+2], xq[m], zd[2][m]);
        float zo = fmaf(WXD[h4+3], xq[m], zd[3][m]);
        c0[m] = sigm(zf)*c0[m] + sigm(zi)*tanhf(zg);
        ov[m] = sigm(zo)*tanhf(c0[m]);
      }
      *reinterpret_cast<float4*>(st) = o;
    }
    gridbar_g(P.flags, P.rel, bgen, bh, uw); ++bgen;

    float y[4][4];
    #pragma unroll
    for (int g = 0; g < 4; ++g)
      #pragma unroll
      for (int m = 0; m < 4; ++m)
        y[g][m] = (kh==0) ? BS[h8+g] : 0.f;
    {
      const float* __restrict__ h0c = P.H0 + (size_t)(q&1)*SP + boff;
      const float* __restrict__ h1q = P.H1 + (size_t)((q+1)&1)*SP + boff;
      const int kb = kh*128, ke = kb + 128;
      #pragma unroll 4
      for (int k = kb; k < ke; ++k) {
        const float4 w1 = *reinterpret_cast<const float4*>(&WA[k][h8]);
        const float4 w2 = *reinterpret_cast<const float4*>(&WA[k][h8+4]);
        const float4 av4 = *reinterpret_cast<const float4*>(&h0c[k*Bb]);
        const float4 dv4 = *reinterpret_cast<const float4*>(&h1q[k*Bb]);
        const float* av = &av4.x;
        const float* dv = &dv4.x;
        #pragma unroll
        for (int m = 0; m < 4; ++m) {
          y[0][m]=fmaf(w1.x,av[m],y[0][m]); y[1][m]=fmaf(w1.y,av[m],y[1][m]);
          y[2][m]=fmaf(w1.z,av[m],y[2][m]); y[3][m]=fmaf(w1.w,av[m],y[3][m]);
          y[0][m]=fmaf(w2.x,dv[m],y[0][m]); y[1][m]=fmaf(w2.y,dv[m],y[1][m]);
          y[2][m]=fmaf(w2.z,dv[m],y[2][m]); y[3][m]=fmaf(w2.w,dv[m],y[3][m]);
        }
      }
    }
    if (kh >= 2) {
      float* r = &RED[kh-2][slot][0];
      #pragma unroll
      for (int g = 0; g < 4; ++g)
        *reinterpret_cast<float4*>(&r[g*4]) = make_float4(y[g][0],y[g][1],y[g][2],y[g][3]);
    }
    __syncthreads();
    if (kh < 2) {
      float* r = &RED[kh][slot][0];
      #pragma unroll
      for (int g = 0; g < 4; ++g) {
        const float4 v = *reinterpret_cast<const float4*>(&r[g*4]);
        y[g][0]+=v.x; y[g][1]+=v.y; y[g][2]+=v.z; y[g][3]+=v.w;
      }
      if (kh == 1) {
        #pragma unroll
        for (int g = 0; g < 4; ++g)
          *reinterpret_cast<float4*>(&r[g*4]) = make_float4(y[g][0],y[g][1],y[g][2],y[g][3]);
      }
    }
    __syncthreads();
    if (kh == 0) {
      const float* r = &RED[1][slot][0];
      #pragma unroll
      for (int g = 0; g < 4; ++g) {
        const float4 v = *reinterpret_cast<const float4*>(&r[g*4]);
        y[g][0]+=v.x; y[g][1]+=v.y; y[g][2]+=v.z; y[g][3]+=v.w;
      }
      float* st = P.H1 + (size_t)(q&1)*SP + (size_t)j*Bb + boff;
      float4 o; float* ov = &o.x;
      #pragma unroll
      for (int m = 0; m < 4; ++m) {
        c1[m] = sigm(y[1][m])*c1[m] + sigm(y[0][m])*tanhf(y[2][m]);
        ov[m] = sigm(y[3][m])*tanhf(c1[m]);
      }
      *reinterpret_cast<float4*>(st) = o;
    }
    gridbar_g(P.flags, P.rel, bgen, bh, uw); ++bgen;
  }

  // ---- final y(OUT-1) ----
  if (kh == 0 && uw == 0 && h == 0) {
    const float* __restrict__ h1f = P.H1 + (size_t)((OUTn-1)&1)*SP + boff;
    float acc[4] = {PBs, PBs, PBs, PBs};
    #pragma unroll 4
    for (int k = 0; k < Hh; ++k) {
      float pw = PW[k];
      const float4 hp4 = *reinterpret_cast<const float4*>(&h1f[k*Bb]);
      const float* hp = &hp4.x;
      #pragma unroll
      for (int m = 0; m < 4; ++m) acc[m] = fmaf(pw, hp[m], acc[m]);
    }
    #pragma unroll
    for (int m = 0; m < 4; ++m) P.out[(size_t)(boff + m)*OUTn + (OUTn-1)] = acc[m];
  }
}

extern "C" void kernel_launch(void* const* d_in, const int* in_sizes, int n_in,
                              void* d_out, int out_size, void* d_ws, size_t ws_size,
                              hipStream_t stream) {
  Params P;
  const float* X = (const float*)d_in[0];
  P.Wih0  = (const float*)d_in[1];  P.Whh0  = (const float*)d_in[2];
  P.bih0  = (const float*)d_in[3];  P.bhh0  = (const float*)d_in[4];
  P.Wih1  = (const float*)d_in[5];  P.Whh1  = (const float*)d_in[6];
  P.bih1  = (const float*)d_in[7];  P.bhh1  = (const float*)d_in[8];
  P.dWih0 = (const float*)d_in[9];  P.dWhh0 = (const float*)d_in[10];
  P.dbih0 = (const float*)d_in[11]; P.dbhh0 = (const float*)d_in[12];
  P.dWih1 = (const float*)d_in[13]; P.dWhh1 = (const float*)d_in[14];
  P.dbih1 = (const float*)d_in[15]; P.dbhh1 = (const float*)d_in[16];
  P.projW = (const float*)d_in[17]; P.projb = (const float*)d_in[18];

  float* ws = (float*)d_ws;
  P.flags = (unsigned int*)ws;          // [2][4096] group flags
  P.rel   = (unsigned int*)ws + 8192;   // rel[0], rel[64]
  P.H0  = ws + HDR;                     // [2][H][B]
  P.H1  = ws + HDR + 2*SP;              // [2][H][B]
  float* Xt = ws + HDR + 4*SP;          // [T][IN][B]
  P.Xt  = Xt;
  P.out = (float*)d_out;

  hipMemsetAsync(d_ws, 0, (size_t)(HDR + 4*SP)*sizeof(float), stream);
  hipLaunchKernelGGL(xpose, dim3(Tt), dim3(256), 0, stream, X, Xt);

  void* args[] = { &P };
  hipLaunchCooperativeKernel((void*)lstm_main, dim3(NWG), dim3(TPB), args, 0, stream);
}